// Round 4
// baseline (927.311 us; speedup 1.0000x reference)
//
#include <hip/hip_runtime.h>
#include <stdint.h>

// cWCT: out = Ls * inv(Lc) * (xc - mu_c) + mu_s, per batch b (B=8, N=512, M=4096)
//
// Pipeline (all bf16 MFMA except Cholesky panel math, fp32 accumulate everywhere):
//  K1 k_meanconv: row means, center, fp32->bf16  (Yc, Ys row-major [512][4096])
//  K2 k_covp:     cov partials = Y*Y^T/4095, K split in 2 (320 WGs): split0 ->
//                 covA lower tiles, split1 -> packed covB (scratch in L16 region)
//  K2b k_covfix:  covA += covB (coalesced), then memset L16 region
//  K3 k_chol:     left-looking blocked Cholesky (NB=32), 16 WGs x 512 thr.
//                 wave0 {diag update (prefetched) + FUSED factor+inv(L1)
//                 shuffle recurrence} || waves1-7 {below-rows update (prefetched)
//                 -> bf16 Pb}; trsm = Pb*inv(L1)^T via MFMA. 2 barriers/panel.
//  K4 k_trinv:    U = inv(Lc), block forward substitution, writes U^T bf16
//  K5 k_tprod:    T = Ls*U  == NT-gemm(Ls, U^T), lower tiles, bf16 out
//  K6 k_out:      out = T*Yc + mu_s (A NT-friendly, B transposed via LDS)
//
// ws layout (bytes), total 100,679,680:
//   Ycb  bf16 [8][512][4096]   @ 0         (33,554,432)
//   Ysb  bf16 [8][512][4096]   @ 33554432  (33,554,432)   (contiguous with Ycb)
//   covA f32  [16][512][512]   @ 67108864  (16,777,216)   (covc then covs)
//   L16  bf16 [16][512][512]   @ 83886080  ( 8,388,608)   (Lc16 then Ls16)
//   Ut16 bf16 [8][512][512]    @ 92274688  ( 4,194,304)
//   T16  bf16 [8][512][512]    @ 96468992  ( 4,194,304)
//   mus  f32  [8][512]         @ 100663296 (    16,384)
//   covB f32  [160][16384]     @ 83886080  (10,485,760)  scratch, dead after
//                                                        k_covfix (memset then)

using short8   = __attribute__((ext_vector_type(8))) short;
using short4_t = __attribute__((ext_vector_type(4))) short;
using f32x4    = __attribute__((ext_vector_type(4))) float;

#define DEVI static __device__ __forceinline__

DEVI uint16_t f32_to_bf16(float f) {
  union { float f; uint32_t u; } v{f};
  uint32_t u = v.u;
  return (uint16_t)((u + 0x7fffu + ((u >> 16) & 1u)) >> 16);  // RNE
}

DEVI f32x4 mfma16(short8 a, short8 b, f32x4 c) {
  return __builtin_amdgcn_mfma_f32_16x16x32_bf16(a, b, c, 0, 0, 0);
}

typedef __attribute__((address_space(3))) uint32_t lds_u32;
typedef __attribute__((address_space(1))) const uint32_t gmem_u32;

DEVI void async_cp16(const uint16_t* g, uint16_t* l) {
  __builtin_amdgcn_global_load_lds((gmem_u32*)g, (lds_u32*)l, 16, 0, 0);
}

// Stage 128x64 bf16 tile from row-major global into LDS via global_load_lds
// (width 16). LDS row r = 64 bf16 = 8 chunks of 16B; physical slot s of row r
// holds logical chunk (s ^ (r&7)) -> 2-way-max bank aliasing on b128 frag reads.
DEVI void stage_tile(const uint16_t* __restrict__ src, int stride,
                     uint16_t* lds, int tid) {
  int w64 = (tid >> 6) << 6;  // wave-uniform
  #pragma unroll
  for (int i = 0; i < 4; ++i) {
    int f = i * 256 + tid;
    int r = f >> 3, s = f & 7;
    int c = s ^ (r & 7);
    async_cp16(src + r * stride + c * 8, lds + (i * 256 + w64) * 8);
  }
}

DEVI short8 frag_ld(const uint16_t* lds, int r, int ch) {
  return *(const short8*)(lds + r * 64 + ((ch ^ (r & 7)) * 8));
}

// ---------------------------------------------------------------- K1: means + center + bf16
__global__ __launch_bounds__(256) void k_meanconv(
    const float* __restrict__ cont, const float* __restrict__ styl,
    uint16_t* __restrict__ Yc, uint16_t* __restrict__ Ys, float* __restrict__ mus) {
  int rid = blockIdx.x;            // 0..8191
  int row = rid & 4095;            // (b*512 + n)
  bool is_s = rid >= 4096;
  const float* src = (is_s ? styl : cont) + (size_t)row * 4096;
  uint16_t* dst = (is_s ? Ys : Yc) + (size_t)row * 4096;
  int tid = threadIdx.x, lane = tid & 63, w = tid >> 6;

  float4 v[4];
  #pragma unroll
  for (int i = 0; i < 4; ++i) v[i] = ((const float4*)src)[i * 256 + tid];
  float s = 0.f;
  #pragma unroll
  for (int i = 0; i < 4; ++i) s += v[i].x + v[i].y + v[i].z + v[i].w;
  #pragma unroll
  for (int off = 32; off > 0; off >>= 1) s += __shfl_down(s, off);
  __shared__ float red[4];
  if (lane == 0) red[w] = s;
  __syncthreads();
  float mean = (red[0] + red[1] + red[2] + red[3]) * (1.0f / 4096.0f);
  if (is_s && tid == 0) mus[row] = mean;

  #pragma unroll
  for (int i = 0; i < 4; ++i) {
    short4_t o;
    o[0] = (short)f32_to_bf16(v[i].x - mean);
    o[1] = (short)f32_to_bf16(v[i].y - mean);
    o[2] = (short)f32_to_bf16(v[i].z - mean);
    o[3] = (short)f32_to_bf16(v[i].w - mean);
    ((short4_t*)dst)[i * 256 + tid] = o;
  }
}

// ---------------------------------------------------------------- K2: cov partials (K-split 2)
__global__ __launch_bounds__(256) void k_covp(const uint16_t* __restrict__ Y,
                                              float* __restrict__ covA,
                                              float* __restrict__ covB) {
  int bx = blockIdx.x;             // 16 mats * 10 lower tiles * 2 splits
  int split = bx & 1, rest = bx >> 1;
  int mat = rest / 10, q = rest % 10;
  int it = (q >= 6) ? 3 : (q >= 3) ? 2 : (q >= 1) ? 1 : 0;
  int jt = q - it * (it + 1) / 2;
  const uint16_t* A = Y + (size_t)mat * 2097152;
  float* C = covA + (size_t)mat * 262144;
  __shared__ uint16_t Al[128 * 64], Bl[128 * 64];
  int tid = threadIdx.x, lane = tid & 63, w = tid >> 6;
  int wr = w >> 1, wc = w & 1, m16 = lane & 15, q4 = lane >> 4;

  f32x4 acc[4][4] = {};
  for (int kb = split * 32; kb < split * 32 + 32; ++kb) {
    __syncthreads();
    stage_tile(A + it * 128 * 4096 + kb * 64, 4096, Al, tid);
    stage_tile(A + jt * 128 * 4096 + kb * 64, 4096, Bl, tid);
    __syncthreads();
    #pragma unroll
    for (int ks = 0; ks < 2; ++ks) {
      short8 af[4], bg[4];
      #pragma unroll
      for (int t = 0; t < 4; ++t) af[t] = frag_ld(Al, wr * 64 + t * 16 + m16, ks * 4 + q4);
      #pragma unroll
      for (int t = 0; t < 4; ++t) bg[t] = frag_ld(Bl, wc * 64 + t * 16 + m16, ks * 4 + q4);
      #pragma unroll
      for (int i2 = 0; i2 < 4; ++i2)
        #pragma unroll
        for (int j2 = 0; j2 < 4; ++j2)
          acc[i2][j2] = mfma16(af[i2], bg[j2], acc[i2][j2]);
    }
  }
  const float sc = 1.0f / 4095.0f;
  if (split == 0) {
    #pragma unroll
    for (int t = 0; t < 4; ++t)
      #pragma unroll
      for (int u = 0; u < 4; ++u)
        #pragma unroll
        for (int g = 0; g < 4; ++g) {
          int row = it * 128 + wr * 64 + t * 16 + q4 * 4 + g;
          int col = jt * 128 + wc * 64 + u * 16 + m16;
          C[row * 512 + col] = acc[t][u][g] * sc;
        }
  } else {
    float* Bp = covB + (size_t)rest * 16384;   // packed [128][128]
    #pragma unroll
    for (int t = 0; t < 4; ++t)
      #pragma unroll
      for (int u = 0; u < 4; ++u)
        #pragma unroll
        for (int g = 0; g < 4; ++g) {
          int row = wr * 64 + t * 16 + q4 * 4 + g;
          int col = wc * 64 + u * 16 + m16;
          Bp[row * 128 + col] = acc[t][u][g] * sc;
        }
  }
}

// ---------------------------------------------------------------- K2b: covA += covB
__global__ __launch_bounds__(256) void k_covfix(float* __restrict__ covA,
                                                const float* __restrict__ covB) {
  int bx = blockIdx.x;             // 160 = mat*10 + q
  int mat = bx / 10, q = bx % 10;
  int it = (q >= 6) ? 3 : (q >= 3) ? 2 : (q >= 1) ? 1 : 0;
  int jt = q - it * (it + 1) / 2;
  float* C = covA + (size_t)mat * 262144;
  const float* Bp = covB + (size_t)bx * 16384;
  for (int e = threadIdx.x; e < 16384; e += 256) {
    int r = e >> 7, c = e & 127;
    C[(it * 128 + r) * 512 + jt * 128 + c] += Bp[e];
  }
}

// ---------------------------------------------------------------- K3: batched Cholesky
// Left-looking, NB=32, one WG (512 thr) per matrix. Per panel j (2 barriers):
//  Phase L: load panel cols [c0,c0+32) rows [c0,512) (original cov) -> P fp32.
//  Phase B: wave0: diag-block update (branchless prefetch MFMA chain) ->
//                  FUSED factor + inv(L1): per step t, the (31-t) factor shfls
//                  and the (t+1) Minv shfls are independent streams -> latency
//                  of each hides the other. Writebacks after the loop.
//           waves1-7: below-rows update (branchless prefetch), Pb = bf16.
//  Phase C: all waves: X = Pb * Mb^T via MFMA (trsm by inverse), write C fp32 +
//           L16 bf16.
__global__ __launch_bounds__(512) void k_chol(float* __restrict__ covA,
                                              uint16_t* __restrict__ L16) {
  int mat = blockIdx.x;
  float* C = covA + (size_t)mat * 262144;
  uint16_t* L = L16 + (size_t)mat * 262144;
  __shared__ float P[512 * 36];        // fp32 panel, pad 36 (rows 16B-aligned)
  __shared__ uint16_t Pb[512 * 40];    // bf16 updated below-diag panel rows
  __shared__ uint16_t Mb[32 * 40];     // bf16 inv(L1)
  int tid = threadIdx.x, lane = tid & 63, w = tid >> 6;
  int m16 = lane & 15, q4 = lane >> 4;

  for (int j = 0; j < 16; ++j) {
    int c0 = j * 32, n = 512 - c0;

    // ---------------- Phase L: panel load (original cov, untouched by prior j)
    for (int e = tid; e < n * 8; e += 512) {
      int r = e >> 3, c4 = e & 7;
      *(float4*)&P[r * 36 + c4 * 4] =
          *(const float4*)(C + (size_t)(c0 + r) * 512 + c0 + c4 * 4);
    }
    __syncthreads();

    // ---------------- Phase B
    if (w == 0) {
      // diag-block update: lower 3 of the 2x2 16-tiles, K = c0, prefetch depth 1
      if (c0 > 0) {
        f32x4 t00 = {}, t10 = {}, t11 = {};
        const uint16_t* L0  = L + (size_t)(c0 + m16) * 512 + q4 * 8;
        const uint16_t* L1r = L + (size_t)(c0 + 16 + m16) * 512 + q4 * 8;
        short8 f0 = *(const short8*)(L0);
        short8 f1 = *(const short8*)(L1r);
        for (int kk = 0; kk < c0; kk += 32) {
          int kn = (kk + 32 < c0) ? kk + 32 : kk;   // branchless clamp
          short8 g0 = *(const short8*)(L0 + kn);
          short8 g1 = *(const short8*)(L1r + kn);
          t00 = mfma16(f0, f0, t00);
          t10 = mfma16(f1, f0, t10);
          t11 = mfma16(f1, f1, t11);
          f0 = g0; f1 = g1;
        }
        #pragma unroll
        for (int g = 0; g < 4; ++g) {
          int r0 = q4 * 4 + g;
          P[r0 * 36 + m16]              -= t00[g];
          P[(16 + r0) * 36 + m16]       -= t10[g];
          P[(16 + r0) * 36 + 16 + m16]  -= t11[g];
        }
      }
      if (lane < 32) {
        int r = lane;
        bool needM = (n > 32);
        float a[32];
        #pragma unroll
        for (int c4 = 0; c4 < 8; ++c4) {
          float4 v = *(const float4*)&P[r * 36 + c4 * 4];
          a[c4 * 4 + 0] = v.x; a[c4 * 4 + 1] = v.y;
          a[c4 * 4 + 2] = v.z; a[c4 * 4 + 3] = v.w;
        }
        // fused factor + Minv. s_[c] accumulates sum_m L[r][m]*M[m][c];
        // lane t finalizes M row t at step t (needs only this step's inv).
        float s_[32], Mrow[32];
        #pragma unroll
        for (int c = 0; c < 32; ++c) { s_[c] = 0.f; Mrow[c] = 0.f; }
        #pragma unroll
        for (int t = 0; t < 32; ++t) {
          float pv  = __shfl(a[t], t);
          float inv = __builtin_amdgcn_rsqf(pv);   // lane-uniform
          a[t] *= inv;                       // L1[r][t]
          float scv = a[t];
          #pragma unroll
          for (int c = t + 1; c < 32; ++c)
            a[c] -= scv * __shfl(scv, c);    // factor stream
          if (needM) {
            #pragma unroll
            for (int c = 0; c <= t; ++c) {   // Minv stream (independent shfls)
              float fin = (((c == t) ? 1.0f : 0.0f) - s_[c]) * inv;
              float mvt = __shfl(fin, t);    // lane t's finalized M[t][c]
              if (r == t) Mrow[c] = fin;
              if (r > t) s_[c] += a[t] * mvt;
            }
          }
        }
        // diag rows writeback (zero upper): covA fp32 + L16 bf16
        float xv[32];
        #pragma unroll
        for (int c = 0; c < 32; ++c) xv[c] = (c <= r) ? a[c] : 0.0f;
        float* Cw = C + (size_t)(c0 + r) * 512 + c0;
        uint16_t* Lw = L + (size_t)(c0 + r) * 512 + c0;
        #pragma unroll
        for (int c4 = 0; c4 < 8; ++c4)
          *(float4*)(Cw + c4 * 4) = make_float4(xv[c4 * 4], xv[c4 * 4 + 1],
                                                xv[c4 * 4 + 2], xv[c4 * 4 + 3]);
        #pragma unroll
        for (int c8 = 0; c8 < 4; ++c8) {
          short8 o;
          #pragma unroll
          for (int u = 0; u < 8; ++u) o[u] = (short)f32_to_bf16(xv[c8 * 8 + u]);
          *(short8*)(Lw + c8 * 8) = o;
        }
        if (needM) {
          uint16_t* Mw = Mb + r * 40;
          #pragma unroll
          for (int c8 = 0; c8 < 4; ++c8) {
            short8 o;
            #pragma unroll
            for (int u = 0; u < 8; ++u) o[u] = (short)f32_to_bf16(Mrow[c8 * 8 + u]);
            *(short8*)(Mw + c8 * 8) = o;
          }
        }
      }
    } else {
      // waves 1-7: below-rows left-looking update -> Pb bf16 (prefetch depth 1)
      int ntiles = (n - 32) >> 4;
      const uint16_t* B0 = L + (size_t)(c0 + m16) * 512 + q4 * 8;
      const uint16_t* B1 = L + (size_t)(c0 + 16 + m16) * 512 + q4 * 8;
      for (int t = w - 1; t < ntiles; t += 7) {
        f32x4 acc0 = {}, acc1 = {};
        const uint16_t* Ar = L + (size_t)(c0 + 32 + t * 16 + m16) * 512 + q4 * 8;
        if (c0 > 0) {
          short8 af = *(const short8*)(Ar);
          short8 b0 = *(const short8*)(B0);
          short8 b1 = *(const short8*)(B1);
          for (int kk = 0; kk < c0; kk += 32) {
            int kn = (kk + 32 < c0) ? kk + 32 : kk;   // branchless clamp
            short8 nf = *(const short8*)(Ar + kn);
            short8 n0 = *(const short8*)(B0 + kn);
            short8 n1 = *(const short8*)(B1 + kn);
            acc0 = mfma16(af, b0, acc0);
            acc1 = mfma16(af, b1, acc1);
            af = nf; b0 = n0; b1 = n1;
          }
        }
        #pragma unroll
        for (int g = 0; g < 4; ++g) {
          int pr = 32 + t * 16 + q4 * 4 + g;   // panel-relative row
          float v0 = P[pr * 36 + m16]      - acc0[g];
          float v1 = P[pr * 36 + 16 + m16] - acc1[g];
          Pb[pr * 40 + m16]      = f32_to_bf16(v0);
          Pb[pr * 40 + 16 + m16] = f32_to_bf16(v1);
        }
      }
    }
    __syncthreads();

    // ---------------- Phase C: trsm via MFMA: X = Pb * Mb^T, write C + L16
    if (n > 32) {
      int ntiles = (n - 32) >> 4;
      short8 bm0 = *(const short8*)(Mb + m16 * 40 + q4 * 8);
      short8 bm1 = *(const short8*)(Mb + (16 + m16) * 40 + q4 * 8);
      for (int t = w; t < ntiles; t += 8) {
        short8 af = *(const short8*)(Pb + (size_t)(32 + t * 16 + m16) * 40 + q4 * 8);
        f32x4 x0 = {}, x1 = {};
        x0 = mfma16(af, bm0, x0);
        x1 = mfma16(af, bm1, x1);
        #pragma unroll
        for (int g = 0; g < 4; ++g) {
          int gr = c0 + 32 + t * 16 + q4 * 4 + g;
          float v0 = x0[g], v1 = x1[g];
          C[(size_t)gr * 512 + c0 + m16]      = v0;
          C[(size_t)gr * 512 + c0 + 16 + m16] = v1;
          L[(size_t)gr * 512 + c0 + m16]      = f32_to_bf16(v0);
          L[(size_t)gr * 512 + c0 + 16 + m16] = f32_to_bf16(v1);
        }
      }
    }
    // no barrier needed here: next Phase L touches a different LDS buffer;
    // Pb/Mb rewrites happen only after the next barrier.
  }
}

// ---------------------------------------------------------------- K4: U = inv(Lc), write U^T bf16
// 32 WGs/matrix (256 thr). Wave = 4 columns; block forward substitution over
// 64-row blocks; Lc blocks staged to LDS, per-wave x stash in LDS.
__global__ __launch_bounds__(256) void k_trinv(const float* __restrict__ covA,
                                               uint16_t* __restrict__ Ut) {
  int bx = blockIdx.x;           // 0..255
  int matb = bx >> 5;
  int sub = bx & 31;
  int cb = sub >> 2, colgrp = sub & 3;
  const float* Lm = covA + (size_t)matb * 262144;
  uint16_t* U = Ut + (size_t)matb * 262144;
  int tid = threadIdx.x, lane = tid & 63, w = tid >> 6;
  int j = cb * 64 + colgrp * 16 + w * 4;   // this wave's 4 columns j..j+3

  __shared__ float Bl[64 * 66];
  __shared__ float Xl[4][4][512];

  for (int rb = cb; rb < 8; ++rb) {
    float acc[4];
    #pragma unroll
    for (int c = 0; c < 4; ++c) acc[c] = ((rb * 64 + lane) == (j + c)) ? 1.0f : 0.0f;
    // subtract contributions of previous blocks
    for (int pb = cb; pb < rb; ++pb) {
      __syncthreads();
      for (int e = tid; e < 4096; e += 256)
        Bl[(e >> 6) * 66 + (e & 63)] = Lm[(rb * 64 + (e >> 6)) * 512 + pb * 64 + (e & 63)];
      __syncthreads();
      #pragma unroll 4
      for (int m = 0; m < 64; m += 2) {
        float2 b2 = *(const float2*)&Bl[lane * 66 + m];
        #pragma unroll
        for (int c = 0; c < 4; ++c)
          acc[c] -= b2.x * Xl[w][c][pb * 64 + m] + b2.y * Xl[w][c][pb * 64 + m + 1];
      }
    }
    // diagonal block solve
    __syncthreads();
    for (int e = tid; e < 4096; e += 256)
      Bl[(e >> 6) * 66 + (e & 63)] = Lm[(rb * 64 + (e >> 6)) * 512 + rb * 64 + (e & 63)];
    __syncthreads();
    float invd = __builtin_amdgcn_rcpf(Bl[lane * 66 + lane]);
    #pragma unroll 1
    for (int i = 0; i < 64; ++i) {
      float bcol = Bl[lane * 66 + i];
      if (lane == i) {
        #pragma unroll
        for (int c = 0; c < 4; ++c) acc[c] *= invd;
      }
      float xi[4];
      #pragma unroll
      for (int c = 0; c < 4; ++c) xi[c] = __shfl(acc[c], i);
      if (lane > i) {
        #pragma unroll
        for (int c = 0; c < 4; ++c) acc[c] -= bcol * xi[c];
      }
    }
    #pragma unroll
    for (int c = 0; c < 4; ++c) {
      Xl[w][c][rb * 64 + lane] = acc[c];
      U[(j + c) * 512 + rb * 64 + lane] = f32_to_bf16(acc[c]);  // U^T row = column j+c
    }
  }
}

// ---------------------------------------------------------------- K5: T = Ls * U (NT: B-src = U^T)
__global__ __launch_bounds__(256) void k_tprod(const uint16_t* __restrict__ Ls16,
                                               const uint16_t* __restrict__ Ut16,
                                               uint16_t* __restrict__ T16) {
  int bx = blockIdx.x;             // 8 mats * 10 lower tiles
  int b = bx / 10, q = bx % 10;
  int it = (q >= 6) ? 3 : (q >= 3) ? 2 : (q >= 1) ? 1 : 0;
  int jt = q - it * (it + 1) / 2;
  const uint16_t* A = Ls16 + (size_t)b * 262144;
  const uint16_t* B = Ut16 + (size_t)b * 262144;
  uint16_t* C = T16 + (size_t)b * 262144;
  __shared__ uint16_t Al[128 * 64], Bl[128 * 64];
  int tid = threadIdx.x, lane = tid & 63, w = tid >> 6;
  int wr = w >> 1, wc = w & 1, m16 = lane & 15, q4 = lane >> 4;

  f32x4 acc[4][4] = {};
  for (int kb = jt * 2; kb < (it + 1) * 2; ++kb) {   // k in [jt*128, (it+1)*128)
    __syncthreads();
    stage_tile(A + it * 128 * 512 + kb * 64, 512, Al, tid);
    stage_tile(B + jt * 128 * 512 + kb * 64, 512, Bl, tid);
    __syncthreads();
    #pragma unroll
    for (int ks = 0; ks < 2; ++ks) {
      short8 af[4], bg[4];
      #pragma unroll
      for (int t = 0; t < 4; ++t) af[t] = frag_ld(Al, wr * 64 + t * 16 + m16, ks * 4 + q4);
      #pragma unroll
      for (int t = 0; t < 4; ++t) bg[t] = frag_ld(Bl, wc * 64 + t * 16 + m16, ks * 4 + q4);
      #pragma unroll
      for (int i2 = 0; i2 < 4; ++i2)
        #pragma unroll
        for (int j2 = 0; j2 < 4; ++j2)
          acc[i2][j2] = mfma16(af[i2], bg[j2], acc[i2][j2]);
    }
  }
  #pragma unroll
  for (int t = 0; t < 4; ++t)
    #pragma unroll
    for (int u = 0; u < 4; ++u)
      #pragma unroll
      for (int g = 0; g < 4; ++g) {
        int row = it * 128 + wr * 64 + t * 16 + q4 * 4 + g;
        int col = jt * 128 + wc * 64 + u * 16 + m16;
        C[row * 512 + col] = f32_to_bf16(acc[t][u][g]);
      }
}

// ---------------------------------------------------------------- K6: out = T * Yc + mu_s
__global__ __launch_bounds__(256) void k_out(const uint16_t* __restrict__ T16,
                                             const uint16_t* __restrict__ Ycb,
                                             const float* __restrict__ mus,
                                             float* __restrict__ out) {
  int bx = blockIdx.x;           // 8 * (4 it * 32 mt)
  int b = bx >> 7, q = bx & 127;
  int it = q >> 5, mt = q & 31;
  int m0 = mt * 128;
  const uint16_t* Tm = T16 + (size_t)b * 262144;
  const uint16_t* Y = Ycb + (size_t)b * 2097152;
  __shared__ uint16_t Al[128 * 64];
  __shared__ uint16_t Bt[128 * 68];   // transposed Yc tile [n(spatial)][k(feature)], pad 68
  int tid = threadIdx.x, lane = tid & 63, w = tid >> 6;
  int wr = w >> 1, wc = w & 1, m16 = lane & 15, q4 = lane >> 4;

  f32x4 acc[4][4] = {};
  int kbmax = (it + 1) * 2;   // T lower-triangular: k < (it+1)*128
  for (int kb = 0; kb < kbmax; ++kb) {
    __syncthreads();
    stage_tile(Tm + it * 128 * 512 + kb * 64, 512, Al, tid);
    // transpose-stage Yc tile: feature rows k, spatial cols m0..m0+128
    #pragma unroll
    for (int rep = 0; rep < 2; ++rep) {
      int task = rep * 256 + tid;
      int n8 = task & 15, kp = task >> 4;   // m-octet, feature-pair
      const uint16_t* p = Y + (size_t)(kb * 64 + 2 * kp) * 4096 + m0 + n8 * 8;
      short8 a0 = *(const short8*)p;
      short8 a1 = *(const short8*)(p + 4096);
      #pragma unroll
      for (int u = 0; u < 8; ++u) {
        int n = n8 * 8 + u;
        uint32_t pk = (uint32_t)(uint16_t)a0[u] | ((uint32_t)(uint16_t)a1[u] << 16);
        *(uint32_t*)(Bt + n * 68 + 2 * kp) = pk;
      }
    }
    __syncthreads();
    #pragma unroll
    for (int ks = 0; ks < 2; ++ks) {
      short8 af[4], bg[4];
      #pragma unroll
      for (int t = 0; t < 4; ++t) af[t] = frag_ld(Al, wr * 64 + t * 16 + m16, ks * 4 + q4);
      #pragma unroll
      for (int t = 0; t < 4; ++t) {
        int n = wc * 64 + t * 16 + m16;
        int ko = ks * 4 + q4;
        short8 bb;
        ((short4_t*)&bb)[0] = *(const short4_t*)(Bt + n * 68 + ko * 8);
        ((short4_t*)&bb)[1] = *(const short4_t*)(Bt + n * 68 + ko * 8 + 4);
        bg[t] = bb;
      }
      #pragma unroll
      for (int i2 = 0; i2 < 4; ++i2)
        #pragma unroll
        for (int j2 = 0; j2 < 4; ++j2)
          acc[i2][j2] = mfma16(af[i2], bg[j2], acc[i2][j2]);
    }
  }
  #pragma unroll
  for (int t = 0; t < 4; ++t)
    #pragma unroll
    for (int g = 0; g < 4; ++g) {
      int row = it * 128 + wr * 64 + t * 16 + q4 * 4 + g;
      float mu = mus[b * 512 + row];
      #pragma unroll
      for (int u = 0; u < 4; ++u) {
        int col = m0 + wc * 64 + u * 16 + m16;
        out[(size_t)(b * 512 + row) * 4096 + col] = acc[t][u][g] + mu;
      }
    }
}

// ----------------------------------------------------------------
extern "C" void kernel_launch(void* const* d_in, const int* in_sizes, int n_in,
                              void* d_out, int out_size, void* d_ws, size_t ws_size,
                              hipStream_t stream) {
  const float* cont = (const float*)d_in[0];
  const float* styl = (const float*)d_in[1];
  // d_in[2] (x_real) is unused by the reference's whitening/coloring path.
  float* out = (float*)d_out;
  char* ws = (char*)d_ws;

  uint16_t* Ycb  = (uint16_t*)(ws);                  // + Ysb contiguous
  float*    covA = (float*)(ws + 67108864);          // covc(8) + covs(8)
  uint16_t* L16  = (uint16_t*)(ws + 83886080);       // Lc16(8) + Ls16(8)
  uint16_t* Ut16 = (uint16_t*)(ws + 92274688);
  uint16_t* T16  = (uint16_t*)(ws + 96468992);
  float*    mus  = (float*)(ws + 100663296);
  float*    covB = (float*)(ws + 83886080);          // scratch: overlays L16 region
                                                     // (dead until memset below)

  uint16_t* Ysb  = Ycb + 16777216;
  uint16_t* Ls16 = L16 + 8 * 262144;

  k_meanconv<<<dim3(8192), dim3(256), 0, stream>>>(cont, styl, Ycb, Ysb, mus);
  k_covp    <<<dim3(320),  dim3(256), 0, stream>>>(Ycb, covA, covB);
  k_covfix  <<<dim3(160),  dim3(256), 0, stream>>>(covA, covB);
  // zero L16/Ut16/T16 (contiguous 16 MiB): strict-upper regions must be 0 bf16.
  // Must run AFTER k_covfix (covB overlays this region).
  hipMemsetAsync((void*)L16, 0, 16777216, stream);
  k_chol    <<<dim3(16),   dim3(512), 0, stream>>>(covA, L16);
  k_trinv   <<<dim3(256),  dim3(256), 0, stream>>>(covA, Ut16);
  k_tprod   <<<dim3(80),   dim3(256), 0, stream>>>(Ls16, Ut16, T16);
  k_out     <<<dim3(1024), dim3(256), 0, stream>>>(T16, Ycb, mus, out);
}

// Round 5
// 736.120 us; speedup vs baseline: 1.2597x; 1.2597x over previous
//
#include <hip/hip_runtime.h>
#include <stdint.h>

// cWCT: out = Ls * inv(Lc) * (xc - mu_c) + mu_s, per batch b (B=8, N=512, M=4096)
//
// Pipeline (all bf16 MFMA except Cholesky panel math, fp32 accumulate everywhere):
//  K1 k_meanconv: row means, center, fp32->bf16  (Yc, Ys row-major [512][4096])
//  K2 k_covp:     cov partials = Y*Y^T/4095, K split in 2 (320 WGs): split0 ->
//                 covA lower tiles, split1 -> packed covB (scratch in L16 region)
//  K2b k_covfix:  covA += covB (coalesced), then memset L16 region
//  K3 k_chol:     left-looking blocked Cholesky (NB=32), 16 WGs x 512 thr.
//                 Round-2 structure (measured 253us) + branchless depth-1
//                 prefetch on the two global-reading MFMA chains.
//                 wave0 {diag update + factor + separate inv(L1) recurrence}
//                 || waves1-7 {below-rows update -> bf16 Pb};
//                 trsm = Pb*inv(L1)^T via MFMA. 2 barriers/panel.
//  K4 k_trinv:    U = inv(Lc), block forward substitution, writes U^T bf16
//  K5 k_tprod:    T = Ls*U  == NT-gemm(Ls, U^T), lower tiles, bf16 out
//  K6 k_out:      out = T*Yc + mu_s (A NT-friendly, B transposed via LDS)
//
// ws layout (bytes), total 100,679,680:
//   Ycb  bf16 [8][512][4096]   @ 0         (33,554,432)
//   Ysb  bf16 [8][512][4096]   @ 33554432  (33,554,432)   (contiguous with Ycb)
//   covA f32  [16][512][512]   @ 67108864  (16,777,216)   (covc then covs)
//   L16  bf16 [16][512][512]   @ 83886080  ( 8,388,608)   (Lc16 then Ls16)
//   Ut16 bf16 [8][512][512]    @ 92274688  ( 4,194,304)
//   T16  bf16 [8][512][512]    @ 96468992  ( 4,194,304)
//   mus  f32  [8][512]         @ 100663296 (    16,384)
//   covB f32  [160][16384]     @ 83886080  (10,485,760)  scratch, dead after
//                                                        k_covfix (memset then)

using short8   = __attribute__((ext_vector_type(8))) short;
using short4_t = __attribute__((ext_vector_type(4))) short;
using f32x4    = __attribute__((ext_vector_type(4))) float;

#define DEVI static __device__ __forceinline__

DEVI uint16_t f32_to_bf16(float f) {
  union { float f; uint32_t u; } v{f};
  uint32_t u = v.u;
  return (uint16_t)((u + 0x7fffu + ((u >> 16) & 1u)) >> 16);  // RNE
}

DEVI f32x4 mfma16(short8 a, short8 b, f32x4 c) {
  return __builtin_amdgcn_mfma_f32_16x16x32_bf16(a, b, c, 0, 0, 0);
}

typedef __attribute__((address_space(3))) uint32_t lds_u32;
typedef __attribute__((address_space(1))) const uint32_t gmem_u32;

DEVI void async_cp16(const uint16_t* g, uint16_t* l) {
  __builtin_amdgcn_global_load_lds((gmem_u32*)g, (lds_u32*)l, 16, 0, 0);
}

// Stage 128x64 bf16 tile from row-major global into LDS via global_load_lds
// (width 16). LDS row r = 64 bf16 = 8 chunks of 16B; physical slot s of row r
// holds logical chunk (s ^ (r&7)) -> 2-way-max bank aliasing on b128 frag reads.
DEVI void stage_tile(const uint16_t* __restrict__ src, int stride,
                     uint16_t* lds, int tid) {
  int w64 = (tid >> 6) << 6;  // wave-uniform
  #pragma unroll
  for (int i = 0; i < 4; ++i) {
    int f = i * 256 + tid;
    int r = f >> 3, s = f & 7;
    int c = s ^ (r & 7);
    async_cp16(src + r * stride + c * 8, lds + (i * 256 + w64) * 8);
  }
}

DEVI short8 frag_ld(const uint16_t* lds, int r, int ch) {
  return *(const short8*)(lds + r * 64 + ((ch ^ (r & 7)) * 8));
}

// ---------------------------------------------------------------- K1: means + center + bf16
__global__ __launch_bounds__(256) void k_meanconv(
    const float* __restrict__ cont, const float* __restrict__ styl,
    uint16_t* __restrict__ Yc, uint16_t* __restrict__ Ys, float* __restrict__ mus) {
  int rid = blockIdx.x;            // 0..8191
  int row = rid & 4095;            // (b*512 + n)
  bool is_s = rid >= 4096;
  const float* src = (is_s ? styl : cont) + (size_t)row * 4096;
  uint16_t* dst = (is_s ? Ys : Yc) + (size_t)row * 4096;
  int tid = threadIdx.x, lane = tid & 63, w = tid >> 6;

  float4 v[4];
  #pragma unroll
  for (int i = 0; i < 4; ++i) v[i] = ((const float4*)src)[i * 256 + tid];
  float s = 0.f;
  #pragma unroll
  for (int i = 0; i < 4; ++i) s += v[i].x + v[i].y + v[i].z + v[i].w;
  #pragma unroll
  for (int off = 32; off > 0; off >>= 1) s += __shfl_down(s, off);
  __shared__ float red[4];
  if (lane == 0) red[w] = s;
  __syncthreads();
  float mean = (red[0] + red[1] + red[2] + red[3]) * (1.0f / 4096.0f);
  if (is_s && tid == 0) mus[row] = mean;

  #pragma unroll
  for (int i = 0; i < 4; ++i) {
    short4_t o;
    o[0] = (short)f32_to_bf16(v[i].x - mean);
    o[1] = (short)f32_to_bf16(v[i].y - mean);
    o[2] = (short)f32_to_bf16(v[i].z - mean);
    o[3] = (short)f32_to_bf16(v[i].w - mean);
    ((short4_t*)dst)[i * 256 + tid] = o;
  }
}

// ---------------------------------------------------------------- K2: cov partials (K-split 2)
__global__ __launch_bounds__(256) void k_covp(const uint16_t* __restrict__ Y,
                                              float* __restrict__ covA,
                                              float* __restrict__ covB) {
  int bx = blockIdx.x;             // 16 mats * 10 lower tiles * 2 splits
  int split = bx & 1, rest = bx >> 1;
  int mat = rest / 10, q = rest % 10;
  int it = (q >= 6) ? 3 : (q >= 3) ? 2 : (q >= 1) ? 1 : 0;
  int jt = q - it * (it + 1) / 2;
  const uint16_t* A = Y + (size_t)mat * 2097152;
  float* C = covA + (size_t)mat * 262144;
  __shared__ uint16_t Al[128 * 64], Bl[128 * 64];
  int tid = threadIdx.x, lane = tid & 63, w = tid >> 6;
  int wr = w >> 1, wc = w & 1, m16 = lane & 15, q4 = lane >> 4;

  f32x4 acc[4][4] = {};
  for (int kb = split * 32; kb < split * 32 + 32; ++kb) {
    __syncthreads();
    stage_tile(A + it * 128 * 4096 + kb * 64, 4096, Al, tid);
    stage_tile(A + jt * 128 * 4096 + kb * 64, 4096, Bl, tid);
    __syncthreads();
    #pragma unroll
    for (int ks = 0; ks < 2; ++ks) {
      short8 af[4], bg[4];
      #pragma unroll
      for (int t = 0; t < 4; ++t) af[t] = frag_ld(Al, wr * 64 + t * 16 + m16, ks * 4 + q4);
      #pragma unroll
      for (int t = 0; t < 4; ++t) bg[t] = frag_ld(Bl, wc * 64 + t * 16 + m16, ks * 4 + q4);
      #pragma unroll
      for (int i2 = 0; i2 < 4; ++i2)
        #pragma unroll
        for (int j2 = 0; j2 < 4; ++j2)
          acc[i2][j2] = mfma16(af[i2], bg[j2], acc[i2][j2]);
    }
  }
  const float sc = 1.0f / 4095.0f;
  if (split == 0) {
    #pragma unroll
    for (int t = 0; t < 4; ++t)
      #pragma unroll
      for (int u = 0; u < 4; ++u)
        #pragma unroll
        for (int g = 0; g < 4; ++g) {
          int row = it * 128 + wr * 64 + t * 16 + q4 * 4 + g;
          int col = jt * 128 + wc * 64 + u * 16 + m16;
          C[row * 512 + col] = acc[t][u][g] * sc;
        }
  } else {
    float* Bp = covB + (size_t)rest * 16384;   // packed [128][128]
    #pragma unroll
    for (int t = 0; t < 4; ++t)
      #pragma unroll
      for (int u = 0; u < 4; ++u)
        #pragma unroll
        for (int g = 0; g < 4; ++g) {
          int row = wr * 64 + t * 16 + q4 * 4 + g;
          int col = wc * 64 + u * 16 + m16;
          Bp[row * 128 + col] = acc[t][u][g] * sc;
        }
  }
}

// ---------------------------------------------------------------- K2b: covA += covB
__global__ __launch_bounds__(256) void k_covfix(float* __restrict__ covA,
                                                const float* __restrict__ covB) {
  int bx = blockIdx.x;             // 160 = mat*10 + q
  int mat = bx / 10, q = bx % 10;
  int it = (q >= 6) ? 3 : (q >= 3) ? 2 : (q >= 1) ? 1 : 0;
  int jt = q - it * (it + 1) / 2;
  float* C = covA + (size_t)mat * 262144;
  const float* Bp = covB + (size_t)bx * 16384;
  for (int e = threadIdx.x; e < 16384; e += 256) {
    int r = e >> 7, c = e & 127;
    C[(it * 128 + r) * 512 + jt * 128 + c] += Bp[e];
  }
}

// ---------------------------------------------------------------- K3: batched Cholesky
// Left-looking, NB=32, one WG (512 thr) per matrix. Per panel j (2 barriers):
//  Phase L: load panel cols [c0,c0+32) rows [c0,512) (original cov) -> P fp32.
//  Phase B: wave0: diag-block update (prefetched MFMA chain) -> factor 32x32
//                  (register rows + shuffles) -> diag writeback -> SEPARATE
//                  Minv = inv(L1) shuffle recurrence -> Mb bf16.
//           waves1-7: below-rows update (prefetched MFMA chain) -> Pb bf16.
//  Phase C: all waves: X = Pb * Mb^T via MFMA (trsm by inverse), write C fp32 +
//           L16 bf16.
__global__ __launch_bounds__(512) void k_chol(float* __restrict__ covA,
                                              uint16_t* __restrict__ L16) {
  int mat = blockIdx.x;
  float* C = covA + (size_t)mat * 262144;
  uint16_t* L = L16 + (size_t)mat * 262144;
  __shared__ float P[512 * 36];        // fp32 panel, pad 36 (rows 16B-aligned)
  __shared__ uint16_t Pb[512 * 40];    // bf16 updated below-diag panel rows
  __shared__ uint16_t Mb[32 * 40];     // bf16 inv(L1)
  int tid = threadIdx.x, lane = tid & 63, w = tid >> 6;
  int m16 = lane & 15, q4 = lane >> 4;

  for (int j = 0; j < 16; ++j) {
    int c0 = j * 32, n = 512 - c0;

    // ---------------- Phase L: panel load (original cov, untouched by prior j)
    for (int e = tid; e < n * 8; e += 512) {
      int r = e >> 3, c4 = e & 7;
      *(float4*)&P[r * 36 + c4 * 4] =
          *(const float4*)(C + (size_t)(c0 + r) * 512 + c0 + c4 * 4);
    }
    __syncthreads();

    // ---------------- Phase B
    if (w == 0) {
      // diag-block update: lower 3 of the 2x2 16-tiles, K = c0, prefetch depth 1
      if (c0 > 0) {
        f32x4 t00 = {}, t10 = {}, t11 = {};
        const uint16_t* L0  = L + (size_t)(c0 + m16) * 512 + q4 * 8;
        const uint16_t* L1r = L + (size_t)(c0 + 16 + m16) * 512 + q4 * 8;
        short8 f0 = *(const short8*)(L0);
        short8 f1 = *(const short8*)(L1r);
        for (int kk = 0; kk < c0; kk += 32) {
          int kn = (kk + 32 < c0) ? kk + 32 : kk;   // branchless clamp
          short8 g0 = *(const short8*)(L0 + kn);
          short8 g1 = *(const short8*)(L1r + kn);
          t00 = mfma16(f0, f0, t00);
          t10 = mfma16(f1, f0, t10);
          t11 = mfma16(f1, f1, t11);
          f0 = g0; f1 = g1;
        }
        #pragma unroll
        for (int g = 0; g < 4; ++g) {
          int r0 = q4 * 4 + g;
          P[r0 * 36 + m16]              -= t00[g];
          P[(16 + r0) * 36 + m16]       -= t10[g];
          P[(16 + r0) * 36 + 16 + m16]  -= t11[g];
        }
      }
      if (lane < 32) {
        int r = lane;
        // factor 32x32 diag block (rows in registers, shuffle broadcasts)
        float a[32];
        #pragma unroll
        for (int c4 = 0; c4 < 8; ++c4) {
          float4 v = *(const float4*)&P[r * 36 + c4 * 4];
          a[c4 * 4 + 0] = v.x; a[c4 * 4 + 1] = v.y;
          a[c4 * 4 + 2] = v.z; a[c4 * 4 + 3] = v.w;
        }
        float myinv = 0.f;
        #pragma unroll
        for (int t = 0; t < 32; ++t) {
          float pv  = __shfl(a[t], t);
          float inv = __builtin_amdgcn_rsqf(pv);
          a[t] *= inv;                       // L1[r][t]
          if (r == t) myinv = inv;           // 1/L1[r][r]
          float scv = a[t];
          #pragma unroll
          for (int c = t + 1; c < 32; ++c)
            a[c] -= scv * __shfl(scv, c);    // -= L1[r][t]*L1[c][t]
        }
        // diag rows writeback (zero upper): covA fp32 + L16 bf16
        float xv[32];
        #pragma unroll
        for (int c = 0; c < 32; ++c) xv[c] = (c <= r) ? a[c] : 0.0f;
        float* Cw = C + (size_t)(c0 + r) * 512 + c0;
        uint16_t* Lw = L + (size_t)(c0 + r) * 512 + c0;
        #pragma unroll
        for (int c4 = 0; c4 < 8; ++c4)
          *(float4*)(Cw + c4 * 4) = make_float4(xv[c4 * 4], xv[c4 * 4 + 1],
                                                xv[c4 * 4 + 2], xv[c4 * 4 + 3]);
        #pragma unroll
        for (int c8 = 0; c8 < 4; ++c8) {
          short8 o;
          #pragma unroll
          for (int u = 0; u < 8; ++u) o[u] = (short)f32_to_bf16(xv[c8 * 8 + u]);
          *(short8*)(Lw + c8 * 8) = o;
        }
        // Minv = inv(L1): row r in b[] via forward-substitution recurrence.
        // b init = e_r * invD[r]; step m broadcasts final row m, lanes r>m
        // subtract invD[r]*L1[r][m] * M[m][*].
        if (n > 32) {
          float b[32];
          #pragma unroll
          for (int c = 0; c < 32; ++c) b[c] = (c == r) ? myinv : 0.0f;
          #pragma unroll
          for (int m = 0; m < 31; ++m) {
            float coef = a[m] * myinv;       // garbage for m>=r, guarded below
            #pragma unroll
            for (int c = 0; c <= m; ++c) {
              float v = __shfl(b[c], m);
              if (r > m) b[c] -= coef * v;
            }
          }
          uint16_t* Mw = Mb + r * 40;
          #pragma unroll
          for (int c8 = 0; c8 < 4; ++c8) {
            short8 o;
            #pragma unroll
            for (int u = 0; u < 8; ++u) o[u] = (short)f32_to_bf16(b[c8 * 8 + u]);
            *(short8*)(Mw + c8 * 8) = o;
          }
        }
      }
    } else {
      // waves 1-7: below-rows left-looking update -> Pb bf16 (prefetch depth 1;
      // runs even when c0==0: kk-loop skipped, Pb = bf16(P))
      int ntiles = (n - 32) >> 4;
      const uint16_t* B0 = L + (size_t)(c0 + m16) * 512 + q4 * 8;
      const uint16_t* B1 = L + (size_t)(c0 + 16 + m16) * 512 + q4 * 8;
      for (int t = w - 1; t < ntiles; t += 7) {
        f32x4 acc0 = {}, acc1 = {};
        const uint16_t* Ar = L + (size_t)(c0 + 32 + t * 16 + m16) * 512 + q4 * 8;
        if (c0 > 0) {
          short8 af = *(const short8*)(Ar);
          short8 b0 = *(const short8*)(B0);
          short8 b1 = *(const short8*)(B1);
          for (int kk = 0; kk < c0; kk += 32) {
            int kn = (kk + 32 < c0) ? kk + 32 : kk;   // branchless clamp
            short8 nf = *(const short8*)(Ar + kn);
            short8 n0 = *(const short8*)(B0 + kn);
            short8 n1 = *(const short8*)(B1 + kn);
            acc0 = mfma16(af, b0, acc0);
            acc1 = mfma16(af, b1, acc1);
            af = nf; b0 = n0; b1 = n1;
          }
        }
        #pragma unroll
        for (int g = 0; g < 4; ++g) {
          int pr = 32 + t * 16 + q4 * 4 + g;   // panel-relative row
          float v0 = P[pr * 36 + m16]      - acc0[g];
          float v1 = P[pr * 36 + 16 + m16] - acc1[g];
          Pb[pr * 40 + m16]      = f32_to_bf16(v0);
          Pb[pr * 40 + 16 + m16] = f32_to_bf16(v1);
        }
      }
    }
    __syncthreads();

    // ---------------- Phase C: trsm via MFMA: X = Pb * Mb^T, write C + L16
    if (n > 32) {
      int ntiles = (n - 32) >> 4;
      short8 bm0 = *(const short8*)(Mb + m16 * 40 + q4 * 8);
      short8 bm1 = *(const short8*)(Mb + (16 + m16) * 40 + q4 * 8);
      for (int t = w; t < ntiles; t += 8) {
        short8 af = *(const short8*)(Pb + (size_t)(32 + t * 16 + m16) * 40 + q4 * 8);
        f32x4 x0 = {}, x1 = {};
        x0 = mfma16(af, bm0, x0);
        x1 = mfma16(af, bm1, x1);
        #pragma unroll
        for (int g = 0; g < 4; ++g) {
          int gr = c0 + 32 + t * 16 + q4 * 4 + g;
          float v0 = x0[g], v1 = x1[g];
          C[(size_t)gr * 512 + c0 + m16]      = v0;
          C[(size_t)gr * 512 + c0 + 16 + m16] = v1;
          L[(size_t)gr * 512 + c0 + m16]      = f32_to_bf16(v0);
          L[(size_t)gr * 512 + c0 + 16 + m16] = f32_to_bf16(v1);
        }
      }
    }
    // no barrier needed here: next Phase L touches disjoint C columns and a
    // different LDS buffer; Pb/Mb rewrites happen only after the next barrier.
  }
}

// ---------------------------------------------------------------- K4: U = inv(Lc), write U^T bf16
// 32 WGs/matrix (256 thr). Wave = 4 columns; block forward substitution over
// 64-row blocks; Lc blocks staged to LDS, per-wave x stash in LDS.
__global__ __launch_bounds__(256) void k_trinv(const float* __restrict__ covA,
                                               uint16_t* __restrict__ Ut) {
  int bx = blockIdx.x;           // 0..255
  int matb = bx >> 5;
  int sub = bx & 31;
  int cb = sub >> 2, colgrp = sub & 3;
  const float* Lm = covA + (size_t)matb * 262144;
  uint16_t* U = Ut + (size_t)matb * 262144;
  int tid = threadIdx.x, lane = tid & 63, w = tid >> 6;
  int j = cb * 64 + colgrp * 16 + w * 4;   // this wave's 4 columns j..j+3

  __shared__ float Bl[64 * 66];
  __shared__ float Xl[4][4][512];

  for (int rb = cb; rb < 8; ++rb) {
    float acc[4];
    #pragma unroll
    for (int c = 0; c < 4; ++c) acc[c] = ((rb * 64 + lane) == (j + c)) ? 1.0f : 0.0f;
    // subtract contributions of previous blocks
    for (int pb = cb; pb < rb; ++pb) {
      __syncthreads();
      for (int e = tid; e < 4096; e += 256)
        Bl[(e >> 6) * 66 + (e & 63)] = Lm[(rb * 64 + (e >> 6)) * 512 + pb * 64 + (e & 63)];
      __syncthreads();
      #pragma unroll 4
      for (int m = 0; m < 64; m += 2) {
        float2 b2 = *(const float2*)&Bl[lane * 66 + m];
        #pragma unroll
        for (int c = 0; c < 4; ++c)
          acc[c] -= b2.x * Xl[w][c][pb * 64 + m] + b2.y * Xl[w][c][pb * 64 + m + 1];
      }
    }
    // diagonal block solve
    __syncthreads();
    for (int e = tid; e < 4096; e += 256)
      Bl[(e >> 6) * 66 + (e & 63)] = Lm[(rb * 64 + (e >> 6)) * 512 + rb * 64 + (e & 63)];
    __syncthreads();
    float invd = __builtin_amdgcn_rcpf(Bl[lane * 66 + lane]);
    #pragma unroll 1
    for (int i = 0; i < 64; ++i) {
      float bcol = Bl[lane * 66 + i];
      if (lane == i) {
        #pragma unroll
        for (int c = 0; c < 4; ++c) acc[c] *= invd;
      }
      float xi[4];
      #pragma unroll
      for (int c = 0; c < 4; ++c) xi[c] = __shfl(acc[c], i);
      if (lane > i) {
        #pragma unroll
        for (int c = 0; c < 4; ++c) acc[c] -= bcol * xi[c];
      }
    }
    #pragma unroll
    for (int c = 0; c < 4; ++c) {
      Xl[w][c][rb * 64 + lane] = acc[c];
      U[(j + c) * 512 + rb * 64 + lane] = f32_to_bf16(acc[c]);  // U^T row = column j+c
    }
  }
}

// ---------------------------------------------------------------- K5: T = Ls * U (NT: B-src = U^T)
__global__ __launch_bounds__(256) void k_tprod(const uint16_t* __restrict__ Ls16,
                                               const uint16_t* __restrict__ Ut16,
                                               uint16_t* __restrict__ T16) {
  int bx = blockIdx.x;             // 8 mats * 10 lower tiles
  int b = bx / 10, q = bx % 10;
  int it = (q >= 6) ? 3 : (q >= 3) ? 2 : (q >= 1) ? 1 : 0;
  int jt = q - it * (it + 1) / 2;
  const uint16_t* A = Ls16 + (size_t)b * 262144;
  const uint16_t* B = Ut16 + (size_t)b * 262144;
  uint16_t* C = T16 + (size_t)b * 262144;
  __shared__ uint16_t Al[128 * 64], Bl[128 * 64];
  int tid = threadIdx.x, lane = tid & 63, w = tid >> 6;
  int wr = w >> 1, wc = w & 1, m16 = lane & 15, q4 = lane >> 4;

  f32x4 acc[4][4] = {};
  for (int kb = jt * 2; kb < (it + 1) * 2; ++kb) {   // k in [jt*128, (it+1)*128)
    __syncthreads();
    stage_tile(A + it * 128 * 512 + kb * 64, 512, Al, tid);
    stage_tile(B + jt * 128 * 512 + kb * 64, 512, Bl, tid);
    __syncthreads();
    #pragma unroll
    for (int ks = 0; ks < 2; ++ks) {
      short8 af[4], bg[4];
      #pragma unroll
      for (int t = 0; t < 4; ++t) af[t] = frag_ld(Al, wr * 64 + t * 16 + m16, ks * 4 + q4);
      #pragma unroll
      for (int t = 0; t < 4; ++t) bg[t] = frag_ld(Bl, wc * 64 + t * 16 + m16, ks * 4 + q4);
      #pragma unroll
      for (int i2 = 0; i2 < 4; ++i2)
        #pragma unroll
        for (int j2 = 0; j2 < 4; ++j2)
          acc[i2][j2] = mfma16(af[i2], bg[j2], acc[i2][j2]);
    }
  }
  #pragma unroll
  for (int t = 0; t < 4; ++t)
    #pragma unroll
    for (int u = 0; u < 4; ++u)
      #pragma unroll
      for (int g = 0; g < 4; ++g) {
        int row = it * 128 + wr * 64 + t * 16 + q4 * 4 + g;
        int col = jt * 128 + wc * 64 + u * 16 + m16;
        C[row * 512 + col] = f32_to_bf16(acc[t][u][g]);
      }
}

// ---------------------------------------------------------------- K6: out = T * Yc + mu_s
__global__ __launch_bounds__(256) void k_out(const uint16_t* __restrict__ T16,
                                             const uint16_t* __restrict__ Ycb,
                                             const float* __restrict__ mus,
                                             float* __restrict__ out) {
  int bx = blockIdx.x;           // 8 * (4 it * 32 mt)
  int b = bx >> 7, q = bx & 127;
  int it = q >> 5, mt = q & 31;
  int m0 = mt * 128;
  const uint16_t* Tm = T16 + (size_t)b * 262144;
  const uint16_t* Y = Ycb + (size_t)b * 2097152;
  __shared__ uint16_t Al[128 * 64];
  __shared__ uint16_t Bt[128 * 68];   // transposed Yc tile [n(spatial)][k(feature)], pad 68
  int tid = threadIdx.x, lane = tid & 63, w = tid >> 6;
  int wr = w >> 1, wc = w & 1, m16 = lane & 15, q4 = lane >> 4;

  f32x4 acc[4][4] = {};
  int kbmax = (it + 1) * 2;   // T lower-triangular: k < (it+1)*128
  for (int kb = 0; kb < kbmax; ++kb) {
    __syncthreads();
    stage_tile(Tm + it * 128 * 512 + kb * 64, 512, Al, tid);
    // transpose-stage Yc tile: feature rows k, spatial cols m0..m0+128
    #pragma unroll
    for (int rep = 0; rep < 2; ++rep) {
      int task = rep * 256 + tid;
      int n8 = task & 15, kp = task >> 4;   // m-octet, feature-pair
      const uint16_t* p = Y + (size_t)(kb * 64 + 2 * kp) * 4096 + m0 + n8 * 8;
      short8 a0 = *(const short8*)p;
      short8 a1 = *(const short8*)(p + 4096);
      #pragma unroll
      for (int u = 0; u < 8; ++u) {
        int n = n8 * 8 + u;
        uint32_t pk = (uint32_t)(uint16_t)a0[u] | ((uint32_t)(uint16_t)a1[u] << 16);
        *(uint32_t*)(Bt + n * 68 + 2 * kp) = pk;
      }
    }
    __syncthreads();
    #pragma unroll
    for (int ks = 0; ks < 2; ++ks) {
      short8 af[4], bg[4];
      #pragma unroll
      for (int t = 0; t < 4; ++t) af[t] = frag_ld(Al, wr * 64 + t * 16 + m16, ks * 4 + q4);
      #pragma unroll
      for (int t = 0; t < 4; ++t) {
        int n = wc * 64 + t * 16 + m16;
        int ko = ks * 4 + q4;
        short8 bb;
        ((short4_t*)&bb)[0] = *(const short4_t*)(Bt + n * 68 + ko * 8);
        ((short4_t*)&bb)[1] = *(const short4_t*)(Bt + n * 68 + ko * 8 + 4);
        bg[t] = bb;
      }
      #pragma unroll
      for (int i2 = 0; i2 < 4; ++i2)
        #pragma unroll
        for (int j2 = 0; j2 < 4; ++j2)
          acc[i2][j2] = mfma16(af[i2], bg[j2], acc[i2][j2]);
    }
  }
  #pragma unroll
  for (int t = 0; t < 4; ++t)
    #pragma unroll
    for (int g = 0; g < 4; ++g) {
      int row = it * 128 + wr * 64 + t * 16 + q4 * 4 + g;
      float mu = mus[b * 512 + row];
      #pragma unroll
      for (int u = 0; u < 4; ++u) {
        int col = m0 + wc * 64 + u * 16 + m16;
        out[(size_t)(b * 512 + row) * 4096 + col] = acc[t][u][g] + mu;
      }
    }
}

// ----------------------------------------------------------------
extern "C" void kernel_launch(void* const* d_in, const int* in_sizes, int n_in,
                              void* d_out, int out_size, void* d_ws, size_t ws_size,
                              hipStream_t stream) {
  const float* cont = (const float*)d_in[0];
  const float* styl = (const float*)d_in[1];
  // d_in[2] (x_real) is unused by the reference's whitening/coloring path.
  float* out = (float*)d_out;
  char* ws = (char*)d_ws;

  uint16_t* Ycb  = (uint16_t*)(ws);                  // + Ysb contiguous
  float*    covA = (float*)(ws + 67108864);          // covc(8) + covs(8)
  uint16_t* L16  = (uint16_t*)(ws + 83886080);       // Lc16(8) + Ls16(8)
  uint16_t* Ut16 = (uint16_t*)(ws + 92274688);
  uint16_t* T16  = (uint16_t*)(ws + 96468992);
  float*    mus  = (float*)(ws + 100663296);
  float*    covB = (float*)(ws + 83886080);          // scratch: overlays L16 region
                                                     // (dead until memset below)

  uint16_t* Ysb  = Ycb + 16777216;
  uint16_t* Ls16 = L16 + 8 * 262144;

  k_meanconv<<<dim3(8192), dim3(256), 0, stream>>>(cont, styl, Ycb, Ysb, mus);
  k_covp    <<<dim3(320),  dim3(256), 0, stream>>>(Ycb, covA, covB);
  k_covfix  <<<dim3(160),  dim3(256), 0, stream>>>(covA, covB);
  // zero L16/Ut16/T16 (contiguous 16 MiB): strict-upper regions must be 0 bf16.
  // Must run AFTER k_covfix (covB overlays this region).
  hipMemsetAsync((void*)L16, 0, 16777216, stream);
  k_chol    <<<dim3(16),   dim3(512), 0, stream>>>(covA, L16);
  k_trinv   <<<dim3(256),  dim3(256), 0, stream>>>(covA, Ut16);
  k_tprod   <<<dim3(80),   dim3(256), 0, stream>>>(Ls16, Ut16, T16);
  k_out     <<<dim3(1024), dim3(256), 0, stream>>>(T16, Ycb, mus, out);
}

// Round 6
// 703.094 us; speedup vs baseline: 1.3189x; 1.0470x over previous
//
#include <hip/hip_runtime.h>
#include <stdint.h>

// cWCT: out = Ls * inv(Lc) * (xc - mu_c) + mu_s, per batch b (B=8, N=512, M=4096)
//
// Pipeline (all bf16 MFMA except Cholesky panel math, fp32 accumulate everywhere):
//  K1 k_meanconv: row means, center, fp32->bf16  (Yc, Ys row-major [512][4096])
//  K2 k_covp:     cov partials = Y*Y^T/4095, K split in 2 (320 WGs): split0 ->
//                 covA lower tiles, split1 -> packed covB (scratch in L16 region)
//  K2b k_covfix:  covA += covB (coalesced), then memset L16 region
//  K3 k_chol:     left-looking blocked Cholesky (NB=32), 16 WGs x 512 thr.
//                 Round-2 factor/Minv/trsm (proven 253us) + LDS-staged B-block:
//                 Bblk = L[c0..c0+32][0..c0] staged once per panel; wave0 diag
//                 update reads LDS; waves1-7 A-stream chunk-prefetched 4-deep
//                 (named regs), B from LDS. 3 barriers/panel.
//  K4 k_trinv:    U = inv(Lc), block forward substitution, writes U^T bf16
//  K5 k_tprod:    T = Ls*U  == NT-gemm(Ls, U^T), lower tiles, bf16 out
//  K6 k_out:      out = T*Yc + mu_s (A NT-friendly, B transposed via LDS)
//
// ws layout (bytes), total 100,679,680:
//   Ycb  bf16 [8][512][4096]   @ 0         (33,554,432)
//   Ysb  bf16 [8][512][4096]   @ 33554432  (33,554,432)   (contiguous with Ycb)
//   covA f32  [16][512][512]   @ 67108864  (16,777,216)   (covc then covs)
//   L16  bf16 [16][512][512]   @ 83886080  ( 8,388,608)   (Lc16 then Ls16)
//   Ut16 bf16 [8][512][512]    @ 92274688  ( 4,194,304)
//   T16  bf16 [8][512][512]    @ 96468992  ( 4,194,304)
//   mus  f32  [8][512]         @ 100663296 (    16,384)
//   covB f32  [160][16384]     @ 83886080  (10,485,760)  scratch, dead after
//                                                        k_covfix (memset then)

using short8   = __attribute__((ext_vector_type(8))) short;
using short4_t = __attribute__((ext_vector_type(4))) short;
using f32x4    = __attribute__((ext_vector_type(4))) float;

#define DEVI static __device__ __forceinline__

DEVI uint16_t f32_to_bf16(float f) {
  union { float f; uint32_t u; } v{f};
  uint32_t u = v.u;
  return (uint16_t)((u + 0x7fffu + ((u >> 16) & 1u)) >> 16);  // RNE
}

DEVI f32x4 mfma16(short8 a, short8 b, f32x4 c) {
  return __builtin_amdgcn_mfma_f32_16x16x32_bf16(a, b, c, 0, 0, 0);
}

typedef __attribute__((address_space(3))) uint32_t lds_u32;
typedef __attribute__((address_space(1))) const uint32_t gmem_u32;

DEVI void async_cp16(const uint16_t* g, uint16_t* l) {
  __builtin_amdgcn_global_load_lds((gmem_u32*)g, (lds_u32*)l, 16, 0, 0);
}

// Stage 128x64 bf16 tile from row-major global into LDS via global_load_lds
// (width 16). LDS row r = 64 bf16 = 8 chunks of 16B; physical slot s of row r
// holds logical chunk (s ^ (r&7)) -> 2-way-max bank aliasing on b128 frag reads.
DEVI void stage_tile(const uint16_t* __restrict__ src, int stride,
                     uint16_t* lds, int tid) {
  int w64 = (tid >> 6) << 6;  // wave-uniform
  #pragma unroll
  for (int i = 0; i < 4; ++i) {
    int f = i * 256 + tid;
    int r = f >> 3, s = f & 7;
    int c = s ^ (r & 7);
    async_cp16(src + r * stride + c * 8, lds + (i * 256 + w64) * 8);
  }
}

DEVI short8 frag_ld(const uint16_t* lds, int r, int ch) {
  return *(const short8*)(lds + r * 64 + ((ch ^ (r & 7)) * 8));
}

// ---------------------------------------------------------------- K1: means + center + bf16
__global__ __launch_bounds__(256) void k_meanconv(
    const float* __restrict__ cont, const float* __restrict__ styl,
    uint16_t* __restrict__ Yc, uint16_t* __restrict__ Ys, float* __restrict__ mus) {
  int rid = blockIdx.x;            // 0..8191
  int row = rid & 4095;            // (b*512 + n)
  bool is_s = rid >= 4096;
  const float* src = (is_s ? styl : cont) + (size_t)row * 4096;
  uint16_t* dst = (is_s ? Ys : Yc) + (size_t)row * 4096;
  int tid = threadIdx.x, lane = tid & 63, w = tid >> 6;

  float4 v[4];
  #pragma unroll
  for (int i = 0; i < 4; ++i) v[i] = ((const float4*)src)[i * 256 + tid];
  float s = 0.f;
  #pragma unroll
  for (int i = 0; i < 4; ++i) s += v[i].x + v[i].y + v[i].z + v[i].w;
  #pragma unroll
  for (int off = 32; off > 0; off >>= 1) s += __shfl_down(s, off);
  __shared__ float red[4];
  if (lane == 0) red[w] = s;
  __syncthreads();
  float mean = (red[0] + red[1] + red[2] + red[3]) * (1.0f / 4096.0f);
  if (is_s && tid == 0) mus[row] = mean;

  #pragma unroll
  for (int i = 0; i < 4; ++i) {
    short4_t o;
    o[0] = (short)f32_to_bf16(v[i].x - mean);
    o[1] = (short)f32_to_bf16(v[i].y - mean);
    o[2] = (short)f32_to_bf16(v[i].z - mean);
    o[3] = (short)f32_to_bf16(v[i].w - mean);
    ((short4_t*)dst)[i * 256 + tid] = o;
  }
}

// ---------------------------------------------------------------- K2: cov partials (K-split 2)
__global__ __launch_bounds__(256) void k_covp(const uint16_t* __restrict__ Y,
                                              float* __restrict__ covA,
                                              float* __restrict__ covB) {
  int bx = blockIdx.x;             // 16 mats * 10 lower tiles * 2 splits
  int split = bx & 1, rest = bx >> 1;
  int mat = rest / 10, q = rest % 10;
  int it = (q >= 6) ? 3 : (q >= 3) ? 2 : (q >= 1) ? 1 : 0;
  int jt = q - it * (it + 1) / 2;
  const uint16_t* A = Y + (size_t)mat * 2097152;
  float* C = covA + (size_t)mat * 262144;
  __shared__ uint16_t Al[128 * 64], Bl[128 * 64];
  int tid = threadIdx.x, lane = tid & 63, w = tid >> 6;
  int wr = w >> 1, wc = w & 1, m16 = lane & 15, q4 = lane >> 4;

  f32x4 acc[4][4] = {};
  for (int kb = split * 32; kb < split * 32 + 32; ++kb) {
    __syncthreads();
    stage_tile(A + it * 128 * 4096 + kb * 64, 4096, Al, tid);
    stage_tile(A + jt * 128 * 4096 + kb * 64, 4096, Bl, tid);
    __syncthreads();
    #pragma unroll
    for (int ks = 0; ks < 2; ++ks) {
      short8 af[4], bg[4];
      #pragma unroll
      for (int t = 0; t < 4; ++t) af[t] = frag_ld(Al, wr * 64 + t * 16 + m16, ks * 4 + q4);
      #pragma unroll
      for (int t = 0; t < 4; ++t) bg[t] = frag_ld(Bl, wc * 64 + t * 16 + m16, ks * 4 + q4);
      #pragma unroll
      for (int i2 = 0; i2 < 4; ++i2)
        #pragma unroll
        for (int j2 = 0; j2 < 4; ++j2)
          acc[i2][j2] = mfma16(af[i2], bg[j2], acc[i2][j2]);
    }
  }
  const float sc = 1.0f / 4095.0f;
  if (split == 0) {
    #pragma unroll
    for (int t = 0; t < 4; ++t)
      #pragma unroll
      for (int u = 0; u < 4; ++u)
        #pragma unroll
        for (int g = 0; g < 4; ++g) {
          int row = it * 128 + wr * 64 + t * 16 + q4 * 4 + g;
          int col = jt * 128 + wc * 64 + u * 16 + m16;
          C[row * 512 + col] = acc[t][u][g] * sc;
        }
  } else {
    float* Bp = covB + (size_t)rest * 16384;   // packed [128][128]
    #pragma unroll
    for (int t = 0; t < 4; ++t)
      #pragma unroll
      for (int u = 0; u < 4; ++u)
        #pragma unroll
        for (int g = 0; g < 4; ++g) {
          int row = wr * 64 + t * 16 + q4 * 4 + g;
          int col = wc * 64 + u * 16 + m16;
          Bp[row * 128 + col] = acc[t][u][g] * sc;
        }
  }
}

// ---------------------------------------------------------------- K2b: covA += covB
__global__ __launch_bounds__(256) void k_covfix(float* __restrict__ covA,
                                                const float* __restrict__ covB) {
  int bx = blockIdx.x;             // 160 = mat*10 + q
  int mat = bx / 10, q = bx % 10;
  int it = (q >= 6) ? 3 : (q >= 3) ? 2 : (q >= 1) ? 1 : 0;
  int jt = q - it * (it + 1) / 2;
  float* C = covA + (size_t)mat * 262144;
  const float* Bp = covB + (size_t)bx * 16384;
  for (int e = threadIdx.x; e < 16384; e += 256) {
    int r = e >> 7, c = e & 127;
    C[(it * 128 + r) * 512 + jt * 128 + c] += Bp[e];
  }
}

// ---------------------------------------------------------------- K3: batched Cholesky
// Left-looking, NB=32, one WG (512 thr) per matrix. Per panel j (3 barriers):
//  Phase L: load panel cols [c0,c0+32) rows [c0,512) (original cov) -> P fp32;
//           stage Bblk = L16[c0..c0+32][0..c0] bf16 -> LDS [32][520].
//  Phase B: wave0: diag update reading Bblk (LDS) -> factor 32x32 (register
//                  rows + shuffles) -> diag writeback -> Minv recurrence -> Mb.
//           waves1-7: per tile, A-frags chunk-prefetched 4-deep from global
//                  (named regs, clamped offsets), B-frags from Bblk LDS;
//                  Pb = bf16(P - acc).
//  Phase C: all waves: X = Pb * Mb^T via MFMA (trsm by inverse), write C fp32 +
//           L16 bf16. Trailing barrier (Bblk staging of panel j+1 reads these).
__global__ __launch_bounds__(512) void k_chol(float* __restrict__ covA,
                                              uint16_t* __restrict__ L16) {
  int mat = blockIdx.x;
  float* C = covA + (size_t)mat * 262144;
  uint16_t* L = L16 + (size_t)mat * 262144;
  __shared__ float P[512 * 36];        // fp32 panel, pad 36 (73,728 B)
  __shared__ uint16_t Pb[512 * 40];    // bf16 updated below-diag rows (40,960 B)
  __shared__ uint16_t Bb[32 * 520];    // bf16 B-block, pad 520 (33,280 B)
  __shared__ uint16_t Mb[32 * 40];     // bf16 inv(L1) (2,560 B)
  int tid = threadIdx.x, lane = tid & 63, w = tid >> 6;
  int m16 = lane & 15, q4 = lane >> 4;

  for (int j = 0; j < 16; ++j) {
    int c0 = j * 32, n = 512 - c0;

    // ---------------- Phase L: panel load + B-block staging
    for (int e = tid; e < n * 8; e += 512) {
      int r = e >> 3, c4 = e & 7;
      *(float4*)&P[r * 36 + c4 * 4] =
          *(const float4*)(C + (size_t)(c0 + r) * 512 + c0 + c4 * 4);
    }
    if (c0 > 0) {
      int cpr = c0 >> 3;               // 16B chunks per row
      for (int e = tid; e < 32 * cpr; e += 512) {
        int r = e / cpr, cc = e - r * cpr;
        *(short8*)(Bb + r * 520 + cc * 8) =
            *(const short8*)(L + (size_t)(c0 + r) * 512 + cc * 8);
      }
    }
    __syncthreads();

    // ---------------- Phase B
    if (w == 0) {
      // diag-block update from Bblk (LDS): lower 3 of the 2x2 16-tiles
      if (c0 > 0) {
        f32x4 t00 = {}, t10 = {}, t11 = {};
        #pragma unroll 4
        for (int kk = 0; kk < c0; kk += 32) {
          short8 f0 = *(const short8*)(Bb + m16 * 520 + kk + q4 * 8);
          short8 f1 = *(const short8*)(Bb + (16 + m16) * 520 + kk + q4 * 8);
          t00 = mfma16(f0, f0, t00);
          t10 = mfma16(f1, f0, t10);
          t11 = mfma16(f1, f1, t11);
        }
        #pragma unroll
        for (int g = 0; g < 4; ++g) {
          int r0 = q4 * 4 + g;
          P[r0 * 36 + m16]              -= t00[g];
          P[(16 + r0) * 36 + m16]       -= t10[g];
          P[(16 + r0) * 36 + 16 + m16]  -= t11[g];
        }
      }
      if (lane < 32) {
        int r = lane;
        // factor 32x32 diag block (rows in registers, shuffle broadcasts)
        float a[32];
        #pragma unroll
        for (int c4 = 0; c4 < 8; ++c4) {
          float4 v = *(const float4*)&P[r * 36 + c4 * 4];
          a[c4 * 4 + 0] = v.x; a[c4 * 4 + 1] = v.y;
          a[c4 * 4 + 2] = v.z; a[c4 * 4 + 3] = v.w;
        }
        float myinv = 0.f;
        #pragma unroll
        for (int t = 0; t < 32; ++t) {
          float pv  = __shfl(a[t], t);
          float inv = __builtin_amdgcn_rsqf(pv);
          a[t] *= inv;                       // L1[r][t]
          if (r == t) myinv = inv;           // 1/L1[r][r]
          float scv = a[t];
          #pragma unroll
          for (int c = t + 1; c < 32; ++c)
            a[c] -= scv * __shfl(scv, c);    // -= L1[r][t]*L1[c][t]
        }
        // diag rows writeback (zero upper): covA fp32 + L16 bf16
        float xv[32];
        #pragma unroll
        for (int c = 0; c < 32; ++c) xv[c] = (c <= r) ? a[c] : 0.0f;
        float* Cw = C + (size_t)(c0 + r) * 512 + c0;
        uint16_t* Lw = L + (size_t)(c0 + r) * 512 + c0;
        #pragma unroll
        for (int c4 = 0; c4 < 8; ++c4)
          *(float4*)(Cw + c4 * 4) = make_float4(xv[c4 * 4], xv[c4 * 4 + 1],
                                                xv[c4 * 4 + 2], xv[c4 * 4 + 3]);
        #pragma unroll
        for (int c8 = 0; c8 < 4; ++c8) {
          short8 o;
          #pragma unroll
          for (int u = 0; u < 8; ++u) o[u] = (short)f32_to_bf16(xv[c8 * 8 + u]);
          *(short8*)(Lw + c8 * 8) = o;
        }
        // Minv = inv(L1): row r in b[] via forward-substitution recurrence.
        if (n > 32) {
          float b[32];
          #pragma unroll
          for (int c = 0; c < 32; ++c) b[c] = (c == r) ? myinv : 0.0f;
          #pragma unroll
          for (int m = 0; m < 31; ++m) {
            float coef = a[m] * myinv;       // garbage for m>=r, guarded below
            #pragma unroll
            for (int c = 0; c <= m; ++c) {
              float v = __shfl(b[c], m);
              if (r > m) b[c] -= coef * v;
            }
          }
          uint16_t* Mw = Mb + r * 40;
          #pragma unroll
          for (int c8 = 0; c8 < 4; ++c8) {
            short8 o;
            #pragma unroll
            for (int u = 0; u < 8; ++u) o[u] = (short)f32_to_bf16(b[c8 * 8 + u]);
            *(short8*)(Mw + c8 * 8) = o;
          }
        }
      }
    } else {
      // waves 1-7: below-rows update. A chunk-prefetched 4-deep (named regs),
      // B from Bblk LDS. Runs even when c0==0 (Pb = bf16(P)).
      int ntiles = (n - 32) >> 4;
      for (int t = w - 1; t < ntiles; t += 7) {
        f32x4 acc0 = {}, acc1 = {};
        const uint16_t* Ar = L + (size_t)(c0 + 32 + t * 16 + m16) * 512 + q4 * 8;
        if (c0 > 0) {
#define LDA(dst, kidx) { int ko_ = ((kidx) < c0) ? (kidx) : 0; \
                         dst = *(const short8*)(Ar + ko_); }
#define STEPK(areg, koff) if ((kb + (koff)) < c0) { \
    int kk2 = kb + (koff); \
    short8 b0_ = *(const short8*)(Bb + m16 * 520 + kk2 + q4 * 8); \
    short8 b1_ = *(const short8*)(Bb + (16 + m16) * 520 + kk2 + q4 * 8); \
    acc0 = mfma16(areg, b0_, acc0); \
    acc1 = mfma16(areg, b1_, acc1); }
          short8 a0, a1, a2, a3, p0, p1, p2, p3;
          LDA(p0, 0) LDA(p1, 32) LDA(p2, 64) LDA(p3, 96)
          int nch = (j + 3) >> 2;
          for (int ch = 0; ch < nch; ++ch) {
            int kb = ch * 128, kn2 = kb + 128;
            a0 = p0; a1 = p1; a2 = p2; a3 = p3;
            LDA(p0, kn2) LDA(p1, kn2 + 32) LDA(p2, kn2 + 64) LDA(p3, kn2 + 96)
            STEPK(a0, 0) STEPK(a1, 32) STEPK(a2, 64) STEPK(a3, 96)
          }
#undef LDA
#undef STEPK
        }
        #pragma unroll
        for (int g = 0; g < 4; ++g) {
          int pr = 32 + t * 16 + q4 * 4 + g;   // panel-relative row
          float v0 = P[pr * 36 + m16]      - acc0[g];
          float v1 = P[pr * 36 + 16 + m16] - acc1[g];
          Pb[pr * 40 + m16]      = f32_to_bf16(v0);
          Pb[pr * 40 + 16 + m16] = f32_to_bf16(v1);
        }
      }
    }
    __syncthreads();

    // ---------------- Phase C: trsm via MFMA: X = Pb * Mb^T, write C + L16
    if (n > 32) {
      int ntiles = (n - 32) >> 4;
      short8 bm0 = *(const short8*)(Mb + m16 * 40 + q4 * 8);
      short8 bm1 = *(const short8*)(Mb + (16 + m16) * 40 + q4 * 8);
      for (int t = w; t < ntiles; t += 8) {
        short8 af = *(const short8*)(Pb + (size_t)(32 + t * 16 + m16) * 40 + q4 * 8);
        f32x4 x0 = {}, x1 = {};
        x0 = mfma16(af, bm0, x0);
        x1 = mfma16(af, bm1, x1);
        #pragma unroll
        for (int g = 0; g < 4; ++g) {
          int gr = c0 + 32 + t * 16 + q4 * 4 + g;
          float v0 = x0[g], v1 = x1[g];
          C[(size_t)gr * 512 + c0 + m16]      = v0;
          C[(size_t)gr * 512 + c0 + 16 + m16] = v1;
          L[(size_t)gr * 512 + c0 + m16]      = f32_to_bf16(v0);
          L[(size_t)gr * 512 + c0 + 16 + m16] = f32_to_bf16(v1);
        }
      }
    }
    // barrier: panel j+1's Bblk staging reads the L16 columns written above
    // by OTHER waves.
    __syncthreads();
  }
}

// ---------------------------------------------------------------- K4: U = inv(Lc), write U^T bf16
// 32 WGs/matrix (256 thr). Wave = 4 columns; block forward substitution over
// 64-row blocks; Lc blocks staged to LDS, per-wave x stash in LDS.
__global__ __launch_bounds__(256) void k_trinv(const float* __restrict__ covA,
                                               uint16_t* __restrict__ Ut) {
  int bx = blockIdx.x;           // 0..255
  int matb = bx >> 5;
  int sub = bx & 31;
  int cb = sub >> 2, colgrp = sub & 3;
  const float* Lm = covA + (size_t)matb * 262144;
  uint16_t* U = Ut + (size_t)matb * 262144;
  int tid = threadIdx.x, lane = tid & 63, w = tid >> 6;
  int j = cb * 64 + colgrp * 16 + w * 4;   // this wave's 4 columns j..j+3

  __shared__ float Bl[64 * 66];
  __shared__ float Xl[4][4][512];

  for (int rb = cb; rb < 8; ++rb) {
    float acc[4];
    #pragma unroll
    for (int c = 0; c < 4; ++c) acc[c] = ((rb * 64 + lane) == (j + c)) ? 1.0f : 0.0f;
    // subtract contributions of previous blocks
    for (int pb = cb; pb < rb; ++pb) {
      __syncthreads();
      for (int e = tid; e < 4096; e += 256)
        Bl[(e >> 6) * 66 + (e & 63)] = Lm[(rb * 64 + (e >> 6)) * 512 + pb * 64 + (e & 63)];
      __syncthreads();
      #pragma unroll 4
      for (int m = 0; m < 64; m += 2) {
        float2 b2 = *(const float2*)&Bl[lane * 66 + m];
        #pragma unroll
        for (int c = 0; c < 4; ++c)
          acc[c] -= b2.x * Xl[w][c][pb * 64 + m] + b2.y * Xl[w][c][pb * 64 + m + 1];
      }
    }
    // diagonal block solve
    __syncthreads();
    for (int e = tid; e < 4096; e += 256)
      Bl[(e >> 6) * 66 + (e & 63)] = Lm[(rb * 64 + (e >> 6)) * 512 + rb * 64 + (e & 63)];
    __syncthreads();
    float invd = __builtin_amdgcn_rcpf(Bl[lane * 66 + lane]);
    #pragma unroll 1
    for (int i = 0; i < 64; ++i) {
      float bcol = Bl[lane * 66 + i];
      if (lane == i) {
        #pragma unroll
        for (int c = 0; c < 4; ++c) acc[c] *= invd;
      }
      float xi[4];
      #pragma unroll
      for (int c = 0; c < 4; ++c) xi[c] = __shfl(acc[c], i);
      if (lane > i) {
        #pragma unroll
        for (int c = 0; c < 4; ++c) acc[c] -= bcol * xi[c];
      }
    }
    #pragma unroll
    for (int c = 0; c < 4; ++c) {
      Xl[w][c][rb * 64 + lane] = acc[c];
      U[(j + c) * 512 + rb * 64 + lane] = f32_to_bf16(acc[c]);  // U^T row = column j+c
    }
  }
}

// ---------------------------------------------------------------- K5: T = Ls * U (NT: B-src = U^T)
__global__ __launch_bounds__(256) void k_tprod(const uint16_t* __restrict__ Ls16,
                                               const uint16_t* __restrict__ Ut16,
                                               uint16_t* __restrict__ T16) {
  int bx = blockIdx.x;             // 8 mats * 10 lower tiles
  int b = bx / 10, q = bx % 10;
  int it = (q >= 6) ? 3 : (q >= 3) ? 2 : (q >= 1) ? 1 : 0;
  int jt = q - it * (it + 1) / 2;
  const uint16_t* A = Ls16 + (size_t)b * 262144;
  const uint16_t* B = Ut16 + (size_t)b * 262144;
  uint16_t* C = T16 + (size_t)b * 262144;
  __shared__ uint16_t Al[128 * 64], Bl[128 * 64];
  int tid = threadIdx.x, lane = tid & 63, w = tid >> 6;
  int wr = w >> 1, wc = w & 1, m16 = lane & 15, q4 = lane >> 4;

  f32x4 acc[4][4] = {};
  for (int kb = jt * 2; kb < (it + 1) * 2; ++kb) {   // k in [jt*128, (it+1)*128)
    __syncthreads();
    stage_tile(A + it * 128 * 512 + kb * 64, 512, Al, tid);
    stage_tile(B + jt * 128 * 512 + kb * 64, 512, Bl, tid);
    __syncthreads();
    #pragma unroll
    for (int ks = 0; ks < 2; ++ks) {
      short8 af[4], bg[4];
      #pragma unroll
      for (int t = 0; t < 4; ++t) af[t] = frag_ld(Al, wr * 64 + t * 16 + m16, ks * 4 + q4);
      #pragma unroll
      for (int t = 0; t < 4; ++t) bg[t] = frag_ld(Bl, wc * 64 + t * 16 + m16, ks * 4 + q4);
      #pragma unroll
      for (int i2 = 0; i2 < 4; ++i2)
        #pragma unroll
        for (int j2 = 0; j2 < 4; ++j2)
          acc[i2][j2] = mfma16(af[i2], bg[j2], acc[i2][j2]);
    }
  }
  #pragma unroll
  for (int t = 0; t < 4; ++t)
    #pragma unroll
    for (int u = 0; u < 4; ++u)
      #pragma unroll
      for (int g = 0; g < 4; ++g) {
        int row = it * 128 + wr * 64 + t * 16 + q4 * 4 + g;
        int col = jt * 128 + wc * 64 + u * 16 + m16;
        C[row * 512 + col] = f32_to_bf16(acc[t][u][g]);
      }
}

// ---------------------------------------------------------------- K6: out = T * Yc + mu_s
__global__ __launch_bounds__(256) void k_out(const uint16_t* __restrict__ T16,
                                             const uint16_t* __restrict__ Ycb,
                                             const float* __restrict__ mus,
                                             float* __restrict__ out) {
  int bx = blockIdx.x;           // 8 * (4 it * 32 mt)
  int b = bx >> 7, q = bx & 127;
  int it = q >> 5, mt = q & 31;
  int m0 = mt * 128;
  const uint16_t* Tm = T16 + (size_t)b * 262144;
  const uint16_t* Y = Ycb + (size_t)b * 2097152;
  __shared__ uint16_t Al[128 * 64];
  __shared__ uint16_t Bt[128 * 68];   // transposed Yc tile [n(spatial)][k(feature)], pad 68
  int tid = threadIdx.x, lane = tid & 63, w = tid >> 6;
  int wr = w >> 1, wc = w & 1, m16 = lane & 15, q4 = lane >> 4;

  f32x4 acc[4][4] = {};
  int kbmax = (it + 1) * 2;   // T lower-triangular: k < (it+1)*128
  for (int kb = 0; kb < kbmax; ++kb) {
    __syncthreads();
    stage_tile(Tm + it * 128 * 512 + kb * 64, 512, Al, tid);
    // transpose-stage Yc tile: feature rows k, spatial cols m0..m0+128
    #pragma unroll
    for (int rep = 0; rep < 2; ++rep) {
      int task = rep * 256 + tid;
      int n8 = task & 15, kp = task >> 4;   // m-octet, feature-pair
      const uint16_t* p = Y + (size_t)(kb * 64 + 2 * kp) * 4096 + m0 + n8 * 8;
      short8 a0 = *(const short8*)p;
      short8 a1 = *(const short8*)(p + 4096);
      #pragma unroll
      for (int u = 0; u < 8; ++u) {
        int n = n8 * 8 + u;
        uint32_t pk = (uint32_t)(uint16_t)a0[u] | ((uint32_t)(uint16_t)a1[u] << 16);
        *(uint32_t*)(Bt + n * 68 + 2 * kp) = pk;
      }
    }
    __syncthreads();
    #pragma unroll
    for (int ks = 0; ks < 2; ++ks) {
      short8 af[4], bg[4];
      #pragma unroll
      for (int t = 0; t < 4; ++t) af[t] = frag_ld(Al, wr * 64 + t * 16 + m16, ks * 4 + q4);
      #pragma unroll
      for (int t = 0; t < 4; ++t) {
        int n = wc * 64 + t * 16 + m16;
        int ko = ks * 4 + q4;
        short8 bb;
        ((short4_t*)&bb)[0] = *(const short4_t*)(Bt + n * 68 + ko * 8);
        ((short4_t*)&bb)[1] = *(const short4_t*)(Bt + n * 68 + ko * 8 + 4);
        bg[t] = bb;
      }
      #pragma unroll
      for (int i2 = 0; i2 < 4; ++i2)
        #pragma unroll
        for (int j2 = 0; j2 < 4; ++j2)
          acc[i2][j2] = mfma16(af[i2], bg[j2], acc[i2][j2]);
    }
  }
  #pragma unroll
  for (int t = 0; t < 4; ++t)
    #pragma unroll
    for (int g = 0; g < 4; ++g) {
      int row = it * 128 + wr * 64 + t * 16 + q4 * 4 + g;
      float mu = mus[b * 512 + row];
      #pragma unroll
      for (int u = 0; u < 4; ++u) {
        int col = m0 + wc * 64 + u * 16 + m16;
        out[(size_t)(b * 512 + row) * 4096 + col] = acc[t][u][g] + mu;
      }
    }
}

// ----------------------------------------------------------------
extern "C" void kernel_launch(void* const* d_in, const int* in_sizes, int n_in,
                              void* d_out, int out_size, void* d_ws, size_t ws_size,
                              hipStream_t stream) {
  const float* cont = (const float*)d_in[0];
  const float* styl = (const float*)d_in[1];
  // d_in[2] (x_real) is unused by the reference's whitening/coloring path.
  float* out = (float*)d_out;
  char* ws = (char*)d_ws;

  uint16_t* Ycb  = (uint16_t*)(ws);                  // + Ysb contiguous
  float*    covA = (float*)(ws + 67108864);          // covc(8) + covs(8)
  uint16_t* L16  = (uint16_t*)(ws + 83886080);       // Lc16(8) + Ls16(8)
  uint16_t* Ut16 = (uint16_t*)(ws + 92274688);
  uint16_t* T16  = (uint16_t*)(ws + 96468992);
  float*    mus  = (float*)(ws + 100663296);
  float*    covB = (float*)(ws + 83886080);          // scratch: overlays L16 region
                                                     // (dead until memset below)

  uint16_t* Ysb  = Ycb + 16777216;
  uint16_t* Ls16 = L16 + 8 * 262144;

  k_meanconv<<<dim3(8192), dim3(256), 0, stream>>>(cont, styl, Ycb, Ysb, mus);
  k_covp    <<<dim3(320),  dim3(256), 0, stream>>>(Ycb, covA, covB);
  k_covfix  <<<dim3(160),  dim3(256), 0, stream>>>(covA, covB);
  // zero L16/Ut16/T16 (contiguous 16 MiB): strict-upper regions must be 0 bf16.
  // Must run AFTER k_covfix (covB overlays this region).
  hipMemsetAsync((void*)L16, 0, 16777216, stream);
  k_chol    <<<dim3(16),   dim3(512), 0, stream>>>(covA, L16);
  k_trinv   <<<dim3(256),  dim3(256), 0, stream>>>(covA, Ut16);
  k_tprod   <<<dim3(80),   dim3(256), 0, stream>>>(Ls16, Ut16, T16);
  k_out     <<<dim3(1024), dim3(256), 0, stream>>>(T16, Ycb, mus, out);
}